// Round 9
// baseline (1125.771 us; speedup 1.0000x reference)
//
#include <hip/hip_runtime.h>

#define TT 2048
#define BB 256
#define II 64
#define HH 128
#define CHP 16          // x/gx chunk depth in timesteps
#define NCH (TT / CHP)  // 128 chunks
#define GXS 532         // gx row stride in floats (slot = col*4 + gate, padded)

#define LOG2E  1.4426950408889634f
#define LOG2E2 2.8853900817779268f

typedef __fp16 f16;
typedef __fp16 h2  __attribute__((ext_vector_type(2)));
typedef __fp16 v8h __attribute__((ext_vector_type(8)));
typedef float  v4f __attribute__((ext_vector_type(4)));
typedef int    v4i __attribute__((ext_vector_type(4)));

union HI { int i; h2 h; };
__device__ __forceinline__ h2  i2h(int v) { HI u; u.i = v; return u.h; }
__device__ __forceinline__ int h2i(h2 v)  { HI u; u.h = v; return u.i; }

// v_exp_f32 computes 2^x natively.
__device__ __forceinline__ float fexp2(float x) {
  float r; asm("v_exp_f32 %0, %1" : "=v"(r) : "v"(x)); return r;
}

// Raw barrier: LDS-drain only; global loads/stores stay in flight.
__device__ __forceinline__ void bar_lgkm() {
  asm volatile("s_waitcnt lgkmcnt(0)\n\ts_barrier" ::: "memory");
}

// One block per batch row, 512 threads = 8 waves = 2 waves/SIMD. R8 (i8
// h-projection) with the classifier moved IN-LOOP (single kernel):
//   - R8 measured a consistent ~120-170us gap for the second kernel +
//     inter-kernel overhead; in-loop classifier costs only wave-7 stream
//     issue (reduction overlaps its own MFMA phase, one step behind) and
//     removes the per-step f16 h store + 131MB write + 128MB re-read.
//   - cpart[2][128] double-buffer: producing lanes (q==0) write hst*wc at
//     step s into cpart[s&1]; wave 7 at step s+1 reads cpart[s&1] (barrier-
//     separated), shuffle-reduces 128 values, stores out[s].
//   - gxb r/z slots hold NEGATED preacts (-log2e folded into Wir/Wiz/biases,
//     -invR/-invZ dequant) so both sigmoids skip the negate.
//   - i8 path unchanged from R8: self-consistent k-slot mapping, per-column
//     W scales, h quantized (x127) only as projection input, f32 hst state.
__global__ __launch_bounds__(512, 1) void gru_mfma(
    const float* __restrict__ x,
    const float* __restrict__ Wir, const float* __restrict__ Wiz, const float* __restrict__ Win,
    const float* __restrict__ bir, const float* __restrict__ biz, const float* __restrict__ bin_,
    const float* __restrict__ Whr, const float* __restrict__ Whz, const float* __restrict__ Whn,
    const float* __restrict__ bhn, const float* __restrict__ Wc,  const float* __restrict__ bc,
    float* __restrict__ out)
{
  const int t = threadIdx.x, b = blockIdx.x;
  const int w = t >> 6;     // wave id 0..7
  const int l = t & 63;     // lane
  const int q = l >> 4;     // quad
  const int r = l & 15;
  const int nc = 16 * w + r;   // this lane's output column

  __shared__ __attribute__((aligned(16))) signed char hq8[2][HH];  // i8 h, dbuf
  __shared__ __attribute__((aligned(16))) f16   xch[2][CHP][72];   // x chunks (f16, A-layout)
  __shared__ __attribute__((aligned(16))) float gxb[2][CHP][GXS];  // gx (prescaled), dbuf
  __shared__ float cpart[2][128];                                   // classifier partials, dbuf

  // ---- i8 Wh fragments: frag f, byte j  <->  k = 64f + 16q + j ----
  v4i bqr[2], bqz[2], bqn[2];
  float nivR, nivZ, invN;    // r,z dequant NEGATED (feeds exp2 directly)
  {
    float mr = 1e-20f, mz = 1e-20f, mn = 1e-20f;
    for (int f = 0; f < 2; ++f)
      for (int j = 0; j < 16; ++j) {
        const int k = 64 * f + 16 * q + j;
        mr = fmaxf(mr, fabsf(Whr[k * HH + nc]));
        mz = fmaxf(mz, fabsf(Whz[k * HH + nc]));
        mn = fmaxf(mn, fabsf(Whn[k * HH + nc]));
      }
    mr = fmaxf(mr, __shfl_xor(mr, 16, 64)); mr = fmaxf(mr, __shfl_xor(mr, 32, 64));
    mz = fmaxf(mz, __shfl_xor(mz, 16, 64)); mz = fmaxf(mz, __shfl_xor(mz, 32, 64));
    mn = fmaxf(mn, __shfl_xor(mn, 16, 64)); mn = fmaxf(mn, __shfl_xor(mn, 32, 64));
    const float sr = 127.f / mr, sz = 127.f / mz, sn = 127.f / mn;
    nivR = -LOG2E * mr / 16129.f;   // 127^2
    nivZ = -LOG2E * mz / 16129.f;
    invN =  LOG2E2 * mn / 16129.f;
    for (int f = 0; f < 2; ++f) {
      union { signed char c[16]; v4i v; } ur, uz, un;
      for (int j = 0; j < 16; ++j) {
        const int k = 64 * f + 16 * q + j;
        ur.c[j] = (signed char)(int)rintf(Whr[k * HH + nc] * sr);
        uz.c[j] = (signed char)(int)rintf(Whz[k * HH + nc] * sz);
        un.c[j] = (signed char)(int)rintf(Whn[k * HH + nc] * sn);
      }
      bqr[f] = ur.v; bqz[f] = uz.v; bqn[f] = un.v;
    }
  }

  // ---- f16 Wi fragments for gx precompute. r,z NEGATED-prescaled. ----
  v8h wir[2], wiz[2], win2[2];
  for (int kt = 0; kt < 2; ++kt) {
    v8h vr, vz, vn;
    for (int j = 0; j < 8; ++j) {
      const int kg = 32 * kt + 8 * q + j;
      vr[j] = (f16)(-LOG2E  * Wir[kg * HH + nc]);
      vz[j] = (f16)(-LOG2E  * Wiz[kg * HH + nc]);
      vn[j] = (f16)( LOG2E2 * Win[kg * HH + nc]);
    }
    wir[kt] = vr; wiz[kt] = vz; win2[kt] = vn;
  }

  const float birc = -LOG2E * bir[nc],  bizc = -LOG2E * biz[nc];
  const float binc = LOG2E2 * bin_[nc], bhnc = LOG2E2 * bhn[nc];
  const float wcp = Wc[nc];                 // classifier weight (this col)
  const float bcp = LOG2E * bc[0];          // prescaled classifier bias

  // full gx precompute (prologue only)
  auto precomp_full = [&](int pn, v8h ax0, v8h ax1) {
    v4f cr = {birc, birc, birc, birc};
    v4f cz = {bizc, bizc, bizc, bizc};
    v4f cn = {binc, binc, binc, binc};
    cr = __builtin_amdgcn_mfma_f32_16x16x32_f16(ax0, wir[0],  cr, 0, 0, 0);
    cz = __builtin_amdgcn_mfma_f32_16x16x32_f16(ax0, wiz[0],  cz, 0, 0, 0);
    cn = __builtin_amdgcn_mfma_f32_16x16x32_f16(ax0, win2[0], cn, 0, 0, 0);
    cr = __builtin_amdgcn_mfma_f32_16x16x32_f16(ax1, wir[1],  cr, 0, 0, 0);
    cz = __builtin_amdgcn_mfma_f32_16x16x32_f16(ax1, wiz[1],  cz, 0, 0, 0);
    cn = __builtin_amdgcn_mfma_f32_16x16x32_f16(ax1, win2[1], cn, 0, 0, 0);
    #pragma unroll
    for (int j = 0; j < 4; ++j) {
      v4f pk; pk[0] = cr[j]; pk[1] = cz[j]; pk[2] = cn[j]; pk[3] = 0.f;
      *(v4f*)&gxb[pn][4 * q + j][nc * 4] = pk;
    }
  };

  // ---- prologue: x chunks 0,1 -> LDS; gx chunk 0 ----
  const int xrow = t >> 5, xcol = (t & 31) * 2;   // thread covers 2 f32 of one row
  float2 xr;
  {
    float2 xA = *(const float2*)(x + ((size_t)(0   + xrow) * BB + b) * II + xcol);
    float2 xB = *(const float2*)(x + ((size_t)(CHP + xrow) * BB + b) * II + xcol);
    if (t < HH) { hq8[0][t] = 0; hq8[1][t] = 0; }
    *(int*)&xch[0][xrow][xcol] = h2i(__builtin_amdgcn_cvt_pkrtz(xA.x, xA.y));
    __syncthreads();
    {
      v8h a0x = *(const v8h*)&xch[0][r][8 * q];
      v8h a1x = *(const v8h*)&xch[0][r][32 + 8 * q];
      precomp_full(0, a0x, a1x);
    }
    *(int*)&xch[1][xrow][xcol] = h2i(__builtin_amdgcn_cvt_pkrtz(xB.x, xB.y));
    __syncthreads();
  }

  // gx prefetch register (step 0)
  v4f gp = *(const v4f*)&gxb[0][0][nc * 4];

  v4i ai0 = {0, 0, 0, 0}, ai1 = {0, 0, 0, 0};   // non-(r==0) lanes stay zero
  float hst = 0.f;
  v4f cpr, cpz, cpn;                            // spread-precomp accs

  for (int c = 0; c < NCH; ++c) {
    const int p = c & 1;
    const bool pc = (c + 1 < NCH);   // precompute gx for next chunk?
    const bool ld = (c + 2 < NCH);   // load x for chunk after next?

    // chunk-top reads: ax frags for the spread precompute; global x loads for
    // chunk c+2 (15 steps of latency slack).
    v8h ax0 = {}, ax1 = {};
    if (pc) {
      ax0 = *(const v8h*)&xch[p ^ 1][r][8 * q];
      ax1 = *(const v8h*)&xch[p ^ 1][r][32 + 8 * q];
    }
    if (ld) {
      xr = *(const float2*)(x + ((size_t)((c + 2) * CHP + xrow) * BB + b) * II + xcol);
    }

    #pragma unroll
    for (int sc = 0; sc < CHP; ++sc) {
      const int s = c * CHP + sc;          // affine; sc is a literal
      const int cur = sc & 1, nxt = cur ^ 1;

      // i8 h A-frags (2 reads, r==0 lanes; 16B-aligned)
      if (r == 0) {
        ai0 = *(const v4i*)&hq8[cur][16 * q];
        ai1 = *(const v4i*)&hq8[cur][64 + 16 * q];
      }

      // wave 7: previous step's classifier partials (one step behind;
      // reduction below overlaps this wave's MFMA phase)
      float cred = 0.f;
      if (w == 7 && (sc > 0 || c > 0))
        cred = cpart[nxt][l] + cpart[nxt][64 + l];

      // spread gx precompute: one op per step in the af-wait bubble.
      if (pc) {
        if (sc == 0) {
          v4f ir = {birc, birc, birc, birc};
          cpr = __builtin_amdgcn_mfma_f32_16x16x32_f16(ax0, wir[0], ir, 0, 0, 0);
        } else if (sc == 1) {
          v4f iz = {bizc, bizc, bizc, bizc};
          cpz = __builtin_amdgcn_mfma_f32_16x16x32_f16(ax0, wiz[0], iz, 0, 0, 0);
        } else if (sc == 2) {
          v4f in_ = {binc, binc, binc, binc};
          cpn = __builtin_amdgcn_mfma_f32_16x16x32_f16(ax0, win2[0], in_, 0, 0, 0);
        } else if (sc == 3) {
          cpr = __builtin_amdgcn_mfma_f32_16x16x32_f16(ax1, wir[1], cpr, 0, 0, 0);
        } else if (sc == 4) {
          cpz = __builtin_amdgcn_mfma_f32_16x16x32_f16(ax1, wiz[1], cpz, 0, 0, 0);
        } else if (sc == 5) {
          cpn = __builtin_amdgcn_mfma_f32_16x16x32_f16(ax1, win2[1], cpn, 0, 0, 0);
        } else if (sc >= 6 && sc < 10) {
          const int j = sc - 6;
          v4f pk; pk[0] = cpr[j]; pk[1] = cpz[j]; pk[2] = cpn[j]; pk[3] = 0.f;
          *(v4f*)&gxb[p ^ 1][4 * q + j][nc * 4] = pk;
        }
      }

      // i8 MFMA phase: 2 K-halves x 3 gates, r first / n / z last.
      const v4i zi = {0, 0, 0, 0};
      v4i cr_, cn2, cz_;
      cr_ = __builtin_amdgcn_mfma_i32_16x16x64_i8(ai0, bqr[0], zi, 0, 0, 0);
      cn2 = __builtin_amdgcn_mfma_i32_16x16x64_i8(ai0, bqn[0], zi, 0, 0, 0);
      cz_ = __builtin_amdgcn_mfma_i32_16x16x64_i8(ai0, bqz[0], zi, 0, 0, 0);
      cr_ = __builtin_amdgcn_mfma_i32_16x16x64_i8(ai1, bqr[1], cr_, 0, 0, 0);
      cn2 = __builtin_amdgcn_mfma_i32_16x16x64_i8(ai1, bqn[1], cn2, 0, 0, 0);
      cz_ = __builtin_amdgcn_mfma_i32_16x16x64_i8(ai1, bqz[1], cz_, 0, 0, 0);

      // gx for THIS step (prefetched last step); prefetch next step's now.
      const v4f g = gp;
      if (sc < CHP - 1) {
        gp = *(const v4f*)&gxb[p][sc + 1][nc * 4];
      } else if (c + 1 < NCH) {
        gp = *(const v4f*)&gxb[p ^ 1][0][nc * 4];
      }

      // epilogue: C row 0 = elem 0 of quad-0 lanes; col = nc.
      // g[0],g[1] are NEGATED preacts; nivR/nivZ negated -> exp2 direct.
      if (q == 0) {
        const float rr  = __builtin_amdgcn_rcpf(1.f + fexp2((float)cr_[0] * nivR + g[0]));
        const float anS = (float)cn2[0] * invN + bhnc;
        const float nn  = 1.f - 2.f * __builtin_amdgcn_rcpf(1.f + fexp2(g[2] + rr * anS));
        const float zz  = __builtin_amdgcn_rcpf(1.f + fexp2((float)cz_[0] * nivZ + g[1]));
        hst = nn + zz * (hst - nn);
        hq8[nxt][nc] = (signed char)(int)rintf(hst * 127.f);   // i8 h for next step
        cpart[cur][nc] = hst * wcp;                            // classifier partial
      }

      // wave 7: finish previous step's classifier (overlaps MFMAs above)
      if (w == 7 && (sc > 0 || c > 0)) {
        cred += __shfl_xor(cred, 1, 64);
        cred += __shfl_xor(cred, 2, 64);
        cred += __shfl_xor(cred, 4, 64);
        cred += __shfl_xor(cred, 8, 64);
        cred += __shfl_xor(cred, 16, 64);
        cred += __shfl_xor(cred, 32, 64);
        if (l == 0)
          out[(size_t)(s - 1) * BB + b] =
              __builtin_amdgcn_rcpf(1.f + fexp2(-(LOG2E * cred + bcp)));  // in-flight OK
      }

      // stage chunk c+2's x (loaded at top of this chunk) into xch[p]
      if (sc == CHP - 1 && ld) {
        *(int*)&xch[p][xrow][xcol] = h2i(__builtin_amdgcn_cvt_pkrtz(xr.x, xr.y));
      }

      bar_lgkm();
    }
  }

  // tail: out[TT-1] from cpart[1] (last step s=2047 has cur=1)
  if (w == 7) {
    float cred = cpart[1][l] + cpart[1][64 + l];
    cred += __shfl_xor(cred, 1, 64);
    cred += __shfl_xor(cred, 2, 64);
    cred += __shfl_xor(cred, 4, 64);
    cred += __shfl_xor(cred, 8, 64);
    cred += __shfl_xor(cred, 16, 64);
    cred += __shfl_xor(cred, 32, 64);
    if (l == 0)
      out[(size_t)(TT - 1) * BB + b] =
          __builtin_amdgcn_rcpf(1.f + fexp2(-(LOG2E * cred + bcp)));
  }
}

extern "C" void kernel_launch(void* const* d_in, const int* in_sizes, int n_in,
                              void* d_out, int out_size, void* d_ws, size_t ws_size,
                              hipStream_t stream) {
  const float* x    = (const float*)d_in[0];
  const float* Wir  = (const float*)d_in[1];
  const float* Wiz  = (const float*)d_in[2];
  const float* Win  = (const float*)d_in[3];
  const float* bir  = (const float*)d_in[4];
  const float* biz  = (const float*)d_in[5];
  const float* bin_ = (const float*)d_in[6];
  const float* Whr  = (const float*)d_in[7];
  const float* Whz  = (const float*)d_in[8];
  const float* Whn  = (const float*)d_in[9];
  const float* bhn  = (const float*)d_in[10];
  const float* Wc   = (const float*)d_in[11];
  const float* bc   = (const float*)d_in[12];
  float* out = (float*)d_out;

  gru_mfma<<<dim3(BB), dim3(512), 0, stream>>>(
      x, Wir, Wiz, Win, bir, biz, bin_, Whr, Whz, Whn, bhn, Wc, bc, out);
}

// Round 10
// 797.784 us; speedup vs baseline: 1.4111x; 1.4111x over previous
//
#include <hip/hip_runtime.h>

#define TT 2048
#define BB 256
#define II 64
#define HH 128
#define CHP 16          // x/gx chunk depth in timesteps
#define NCH (TT / CHP)  // 128 chunks
#define GXS 532         // gx row stride in floats (slot = col*4 + gate, padded)

#define LOG2E  1.4426950408889634f
#define LOG2E2 2.8853900817779268f

typedef __fp16 f16;
typedef __fp16 h2  __attribute__((ext_vector_type(2)));
typedef __fp16 v8h __attribute__((ext_vector_type(8)));
typedef float  v4f __attribute__((ext_vector_type(4)));
typedef int    v4i __attribute__((ext_vector_type(4)));

union HI { int i; h2 h; };
__device__ __forceinline__ h2  i2h(int v) { HI u; u.i = v; return u.h; }
__device__ __forceinline__ int h2i(h2 v)  { HI u; u.h = v; return u.i; }

// v_exp_f32 computes 2^x natively.
__device__ __forceinline__ float fexp2(float x) {
  float r; asm("v_exp_f32 %0, %1" : "=v"(r) : "v"(x)); return r;
}

// Raw barrier: LDS-drain only; global loads/stores stay in flight.
__device__ __forceinline__ void bar_lgkm() {
  asm volatile("s_waitcnt lgkmcnt(0)\n\ts_barrier" ::: "memory");
}

// One block per batch row, 512 threads = 8 waves = 2 waves/SIMD. Single
// kernel. R8's i8 step structure, with the classifier done by the MATRIX
// pipe instead of shuffles (R9's lesson: a 6-deep dependent __shfl_xor
// chain on the barrier path cost +450 cyc/step):
//   - bqc[2] = i8 Wc in COLUMN 0 of a 16-wide B tile (same k-slot mapping
//     as the gate fragments; r==0 lanes carry the column, others zero).
//   - wave 7 issues 2 extra i8 MFMAs per step on the already-loaded
//     ai0/ai1 (= h_{s-1}): C[0][0] -> lane 0 elem 0 = dot(h_{s-1}, Wc).
//     HW does the 128-wide reduction; lane 0 applies sigmoid (exp2 form,
//     negated dequant) and fire-and-forget stores out[s-1].
//   - tail step classifies the final h from hq8[0] after the loop.
//   - no h history, no workspace, no second kernel, no cpart LDS.
__global__ __launch_bounds__(512, 1) void gru_mfma(
    const float* __restrict__ x,
    const float* __restrict__ Wir, const float* __restrict__ Wiz, const float* __restrict__ Win,
    const float* __restrict__ bir, const float* __restrict__ biz, const float* __restrict__ bin_,
    const float* __restrict__ Whr, const float* __restrict__ Whz, const float* __restrict__ Whn,
    const float* __restrict__ bhn, const float* __restrict__ Wc,  const float* __restrict__ bc,
    float* __restrict__ out)
{
  const int t = threadIdx.x, b = blockIdx.x;
  const int w = t >> 6;     // wave id 0..7
  const int l = t & 63;     // lane
  const int q = l >> 4;     // quad
  const int r = l & 15;
  const int nc = 16 * w + r;   // this lane's output column

  __shared__ __attribute__((aligned(16))) signed char hq8[2][HH];  // i8 h, dbuf
  __shared__ __attribute__((aligned(16))) f16   xch[2][CHP][72];   // x chunks (f16, A-layout)
  __shared__ __attribute__((aligned(16))) float gxb[2][CHP][GXS];  // gx (prescaled), dbuf

  // ---- i8 Wh fragments: frag f, byte j  <->  k = 64f + 16q + j ----
  v4i bqr[2], bqz[2], bqn[2];
  float nivR, nivZ, invN;    // r,z dequant NEGATED (feeds exp2 directly)
  {
    float mr = 1e-20f, mz = 1e-20f, mn = 1e-20f;
    for (int f = 0; f < 2; ++f)
      for (int j = 0; j < 16; ++j) {
        const int k = 64 * f + 16 * q + j;
        mr = fmaxf(mr, fabsf(Whr[k * HH + nc]));
        mz = fmaxf(mz, fabsf(Whz[k * HH + nc]));
        mn = fmaxf(mn, fabsf(Whn[k * HH + nc]));
      }
    mr = fmaxf(mr, __shfl_xor(mr, 16, 64)); mr = fmaxf(mr, __shfl_xor(mr, 32, 64));
    mz = fmaxf(mz, __shfl_xor(mz, 16, 64)); mz = fmaxf(mz, __shfl_xor(mz, 32, 64));
    mn = fmaxf(mn, __shfl_xor(mn, 16, 64)); mn = fmaxf(mn, __shfl_xor(mn, 32, 64));
    const float sr = 127.f / mr, sz = 127.f / mz, sn = 127.f / mn;
    nivR = -LOG2E * mr / 16129.f;   // 127^2
    nivZ = -LOG2E * mz / 16129.f;
    invN =  LOG2E2 * mn / 16129.f;
    for (int f = 0; f < 2; ++f) {
      union { signed char c[16]; v4i v; } ur, uz, un;
      for (int j = 0; j < 16; ++j) {
        const int k = 64 * f + 16 * q + j;
        ur.c[j] = (signed char)(int)rintf(Whr[k * HH + nc] * sr);
        uz.c[j] = (signed char)(int)rintf(Whz[k * HH + nc] * sz);
        un.c[j] = (signed char)(int)rintf(Whn[k * HH + nc] * sn);
      }
      bqr[f] = ur.v; bqz[f] = uz.v; bqn[f] = un.v;
    }
  }

  // ---- classifier i8 fragment: Wc in column 0 (r==0 lanes), else zero ----
  v4i bqc[2] = {{0, 0, 0, 0}, {0, 0, 0, 0}};
  float nivC, bcn;           // negated dequant + negated prescaled bias
  {
    float m = fmaxf(fabsf(Wc[l]), fabsf(Wc[64 + l]));
    m = fmaxf(m, __shfl_xor(m, 1, 64));  m = fmaxf(m, __shfl_xor(m, 2, 64));
    m = fmaxf(m, __shfl_xor(m, 4, 64));  m = fmaxf(m, __shfl_xor(m, 8, 64));
    m = fmaxf(m, __shfl_xor(m, 16, 64)); m = fmaxf(m, __shfl_xor(m, 32, 64));
    const float sc_ = 127.f / m;
    nivC = -LOG2E * m / 16129.f;
    bcn  = -LOG2E * bc[0];
    if (r == 0) {
      for (int f = 0; f < 2; ++f) {
        union { signed char c[16]; v4i v; } uc;
        for (int j = 0; j < 16; ++j)
          uc.c[j] = (signed char)(int)rintf(Wc[64 * f + 16 * q + j] * sc_);
        bqc[f] = uc.v;
      }
    }
  }

  // ---- f16 Wi fragments for gx precompute. r,z NEGATED-prescaled. ----
  v8h wir[2], wiz[2], win2[2];
  for (int kt = 0; kt < 2; ++kt) {
    v8h vr, vz, vn;
    for (int j = 0; j < 8; ++j) {
      const int kg = 32 * kt + 8 * q + j;
      vr[j] = (f16)(-LOG2E  * Wir[kg * HH + nc]);
      vz[j] = (f16)(-LOG2E  * Wiz[kg * HH + nc]);
      vn[j] = (f16)( LOG2E2 * Win[kg * HH + nc]);
    }
    wir[kt] = vr; wiz[kt] = vz; win2[kt] = vn;
  }

  const float birc = -LOG2E * bir[nc],  bizc = -LOG2E * biz[nc];
  const float binc = LOG2E2 * bin_[nc], bhnc = LOG2E2 * bhn[nc];

  // full gx precompute (prologue only)
  auto precomp_full = [&](int pn, v8h ax0, v8h ax1) {
    v4f cr = {birc, birc, birc, birc};
    v4f cz = {bizc, bizc, bizc, bizc};
    v4f cn = {binc, binc, binc, binc};
    cr = __builtin_amdgcn_mfma_f32_16x16x32_f16(ax0, wir[0],  cr, 0, 0, 0);
    cz = __builtin_amdgcn_mfma_f32_16x16x32_f16(ax0, wiz[0],  cz, 0, 0, 0);
    cn = __builtin_amdgcn_mfma_f32_16x16x32_f16(ax0, win2[0], cn, 0, 0, 0);
    cr = __builtin_amdgcn_mfma_f32_16x16x32_f16(ax1, wir[1],  cr, 0, 0, 0);
    cz = __builtin_amdgcn_mfma_f32_16x16x32_f16(ax1, wiz[1],  cz, 0, 0, 0);
    cn = __builtin_amdgcn_mfma_f32_16x16x32_f16(ax1, win2[1], cn, 0, 0, 0);
    #pragma unroll
    for (int j = 0; j < 4; ++j) {
      v4f pk; pk[0] = cr[j]; pk[1] = cz[j]; pk[2] = cn[j]; pk[3] = 0.f;
      *(v4f*)&gxb[pn][4 * q + j][nc * 4] = pk;
    }
  };

  // ---- prologue: x chunks 0,1 -> LDS; gx chunk 0 ----
  const int xrow = t >> 5, xcol = (t & 31) * 2;   // thread covers 2 f32 of one row
  float2 xr;
  {
    float2 xA = *(const float2*)(x + ((size_t)(0   + xrow) * BB + b) * II + xcol);
    float2 xB = *(const float2*)(x + ((size_t)(CHP + xrow) * BB + b) * II + xcol);
    if (t < HH) { hq8[0][t] = 0; hq8[1][t] = 0; }
    *(int*)&xch[0][xrow][xcol] = h2i(__builtin_amdgcn_cvt_pkrtz(xA.x, xA.y));
    __syncthreads();
    {
      v8h a0x = *(const v8h*)&xch[0][r][8 * q];
      v8h a1x = *(const v8h*)&xch[0][r][32 + 8 * q];
      precomp_full(0, a0x, a1x);
    }
    *(int*)&xch[1][xrow][xcol] = h2i(__builtin_amdgcn_cvt_pkrtz(xB.x, xB.y));
    __syncthreads();
  }

  // gx prefetch register (step 0)
  v4f gp = *(const v4f*)&gxb[0][0][nc * 4];

  v4i ai0 = {0, 0, 0, 0}, ai1 = {0, 0, 0, 0};   // non-(r==0) lanes stay zero
  float hst = 0.f;
  v4f cpr, cpz, cpn;                            // spread-precomp accs
  const v4i zi = {0, 0, 0, 0};

  for (int c = 0; c < NCH; ++c) {
    const int p = c & 1;
    const bool pc = (c + 1 < NCH);   // precompute gx for next chunk?
    const bool ld = (c + 2 < NCH);   // load x for chunk after next?

    // chunk-top reads: ax frags for the spread precompute; global x loads for
    // chunk c+2 (15 steps of latency slack).
    v8h ax0 = {}, ax1 = {};
    if (pc) {
      ax0 = *(const v8h*)&xch[p ^ 1][r][8 * q];
      ax1 = *(const v8h*)&xch[p ^ 1][r][32 + 8 * q];
    }
    if (ld) {
      xr = *(const float2*)(x + ((size_t)((c + 2) * CHP + xrow) * BB + b) * II + xcol);
    }

    #pragma unroll
    for (int sc = 0; sc < CHP; ++sc) {
      const int s = c * CHP + sc;          // affine; sc is a literal
      const int cur = sc & 1, nxt = cur ^ 1;

      // i8 h A-frags (2 reads, r==0 lanes; 16B-aligned)
      if (r == 0) {
        ai0 = *(const v4i*)&hq8[cur][16 * q];
        ai1 = *(const v4i*)&hq8[cur][64 + 16 * q];
      }

      // spread gx precompute: one op per step in the af-wait bubble
      // (f16 MFMAs on registers, no lgkm dependence).
      if (pc) {
        if (sc == 0) {
          v4f ir = {birc, birc, birc, birc};
          cpr = __builtin_amdgcn_mfma_f32_16x16x32_f16(ax0, wir[0], ir, 0, 0, 0);
        } else if (sc == 1) {
          v4f iz = {bizc, bizc, bizc, bizc};
          cpz = __builtin_amdgcn_mfma_f32_16x16x32_f16(ax0, wiz[0], iz, 0, 0, 0);
        } else if (sc == 2) {
          v4f in_ = {binc, binc, binc, binc};
          cpn = __builtin_amdgcn_mfma_f32_16x16x32_f16(ax0, win2[0], in_, 0, 0, 0);
        } else if (sc == 3) {
          cpr = __builtin_amdgcn_mfma_f32_16x16x32_f16(ax1, wir[1], cpr, 0, 0, 0);
        } else if (sc == 4) {
          cpz = __builtin_amdgcn_mfma_f32_16x16x32_f16(ax1, wiz[1], cpz, 0, 0, 0);
        } else if (sc == 5) {
          cpn = __builtin_amdgcn_mfma_f32_16x16x32_f16(ax1, win2[1], cpn, 0, 0, 0);
        } else if (sc >= 6 && sc < 10) {
          const int j = sc - 6;
          v4f pk; pk[0] = cpr[j]; pk[1] = cpz[j]; pk[2] = cpn[j]; pk[3] = 0.f;
          *(v4f*)&gxb[p ^ 1][4 * q + j][nc * 4] = pk;
        }
      }

      // wave 7: classifier MFMAs FIRST (result ready by epilogue time).
      // C[0][0] = dot(h_{s-1}, Wc) lands in lane 0 elem 0.
      v4i cc = zi;
      if (w == 7) {
        cc = __builtin_amdgcn_mfma_i32_16x16x64_i8(ai0, bqc[0], zi, 0, 0, 0);
        cc = __builtin_amdgcn_mfma_i32_16x16x64_i8(ai1, bqc[1], cc, 0, 0, 0);
      }

      // i8 gate MFMA phase: 2 K-halves x 3 gates, r first / n / z last.
      v4i cr_, cn2, cz_;
      cr_ = __builtin_amdgcn_mfma_i32_16x16x64_i8(ai0, bqr[0], zi, 0, 0, 0);
      cn2 = __builtin_amdgcn_mfma_i32_16x16x64_i8(ai0, bqn[0], zi, 0, 0, 0);
      cz_ = __builtin_amdgcn_mfma_i32_16x16x64_i8(ai0, bqz[0], zi, 0, 0, 0);
      cr_ = __builtin_amdgcn_mfma_i32_16x16x64_i8(ai1, bqr[1], cr_, 0, 0, 0);
      cn2 = __builtin_amdgcn_mfma_i32_16x16x64_i8(ai1, bqn[1], cn2, 0, 0, 0);
      cz_ = __builtin_amdgcn_mfma_i32_16x16x64_i8(ai1, bqz[1], cz_, 0, 0, 0);

      // gx for THIS step (prefetched last step); prefetch next step's now.
      const v4f g = gp;
      if (sc < CHP - 1) {
        gp = *(const v4f*)&gxb[p][sc + 1][nc * 4];
      } else if (c + 1 < NCH) {
        gp = *(const v4f*)&gxb[p ^ 1][0][nc * 4];
      }

      // wave 7 lane 0: finish previous step's classifier (one sigmoid+store;
      // in-flight store, never waited on).
      if (w == 7 && (sc > 0 || c > 0) && l == 0) {
        out[(size_t)(s - 1) * BB + b] =
            __builtin_amdgcn_rcpf(1.f + fexp2((float)cc[0] * nivC + bcn));
      }

      // epilogue: C row 0 = elem 0 of quad-0 lanes; col = nc.
      // g[0],g[1] are NEGATED preacts; nivR/nivZ negated -> exp2 direct.
      if (q == 0) {
        const float rr  = __builtin_amdgcn_rcpf(1.f + fexp2((float)cr_[0] * nivR + g[0]));
        const float anS = (float)cn2[0] * invN + bhnc;
        const float nn  = 1.f - 2.f * __builtin_amdgcn_rcpf(1.f + fexp2(g[2] + rr * anS));
        const float zz  = __builtin_amdgcn_rcpf(1.f + fexp2((float)cz_[0] * nivZ + g[1]));
        hst = nn + zz * (hst - nn);
        hq8[nxt][nc] = (signed char)(int)rintf(hst * 127.f);   // i8 h for next step
      }

      // stage chunk c+2's x (loaded at top of this chunk) into xch[p]
      if (sc == CHP - 1 && ld) {
        *(int*)&xch[p][xrow][xcol] = h2i(__builtin_amdgcn_cvt_pkrtz(xr.x, xr.y));
      }

      bar_lgkm();
    }
  }

  // tail: out[TT-1] from hq8[0] (step 2047 wrote nxt==0)
  if (w == 7) {
    v4i a0t = zi, a1t = zi;
    if (r == 0) {
      a0t = *(const v4i*)&hq8[0][16 * q];
      a1t = *(const v4i*)&hq8[0][64 + 16 * q];
    }
    v4i cc = __builtin_amdgcn_mfma_i32_16x16x64_i8(a0t, bqc[0], zi, 0, 0, 0);
    cc = __builtin_amdgcn_mfma_i32_16x16x64_i8(a1t, bqc[1], cc, 0, 0, 0);
    if (l == 0) {
      out[(size_t)(TT - 1) * BB + b] =
          __builtin_amdgcn_rcpf(1.f + fexp2((float)cc[0] * nivC + bcn));
    }
  }
}

extern "C" void kernel_launch(void* const* d_in, const int* in_sizes, int n_in,
                              void* d_out, int out_size, void* d_ws, size_t ws_size,
                              hipStream_t stream) {
  const float* x    = (const float*)d_in[0];
  const float* Wir  = (const float*)d_in[1];
  const float* Wiz  = (const float*)d_in[2];
  const float* Win  = (const float*)d_in[3];
  const float* bir  = (const float*)d_in[4];
  const float* biz  = (const float*)d_in[5];
  const float* bin_ = (const float*)d_in[6];
  const float* Whr  = (const float*)d_in[7];
  const float* Whz  = (const float*)d_in[8];
  const float* Whn  = (const float*)d_in[9];
  const float* bhn  = (const float*)d_in[10];
  const float* Wc   = (const float*)d_in[11];
  const float* bc   = (const float*)d_in[12];
  float* out = (float*)d_out;

  gru_mfma<<<dim3(BB), dim3(512), 0, stream>>>(
      x, Wir, Wiz, Win, bir, biz, bin_, Whr, Whz, Whn, bhn, Wc, bc, out);
}